// Round 9
// baseline (707.841 us; speedup 1.0000x reference)
//
#include <hip/hip_runtime.h>
#include <hip/hip_bf16.h>

#define TT 50
#define BB 64
#define SS 100
#define HH 512
#define VT 32000
#define VE 5000
#define LDC 37000          // VT + VE
#define MROWS 3200         // T*B
#define NTILE 125          // VT/256 column tiles
#define NRT 25             // M row tiles of 128
#define NWG 3125           // NTILE*NRT
#define TSTR 136           // epilogue LDS tile stride (ushorts, 128+8)

typedef __bf16 bf16x8 __attribute__((ext_vector_type(8)));
typedef float f32x4 __attribute__((ext_vector_type(4)));

__device__ __forceinline__ ushort f2bf(float f) {
    unsigned u = __float_as_uint(f);
    u += 0x7fffu + ((u >> 16) & 1u);   // RNE
    return (ushort)(u >> 16);
}
__device__ __forceinline__ float bflo(unsigned u) { return __uint_as_float(u << 16); }
__device__ __forceinline__ float bfhi(unsigned u) { return __uint_as_float(u & 0xffff0000u); }

// ---------------- pass 0: fp32 -> bf16 conversion of W and hidden ----------------
__global__ void convert_kernel(const float* __restrict__ W, const float* __restrict__ hid,
                               ushort* __restrict__ wsB, ushort* __restrict__ wsA) {
    int g = blockIdx.x * 256 + threadIdx.x;
    const int WG = 4096000;                      // W float4-groups
    float4 v;
    ushort* dst;
    if (g < WG) {
        v = ((const float4*)W)[g];
        dst = wsB + 4 * (size_t)g;
    } else {
        int h = g - WG;
        v = ((const float4*)hid)[h];
        dst = wsA + 4 * (size_t)h;
    }
    ushort4 o;
    o.x = f2bf(v.x); o.y = f2bf(v.y); o.z = f2bf(v.z); o.w = f2bf(v.w);
    *(ushort4*)dst = o;
}

// ---------------- pass 1: bf16 MFMA GEMM, 128x256 block, 4 waves, wave 64x128 --------
// C = A[3200x512]*B^T[32000x512] + bias.  16 K-tiles of BK=32, 2-slot LDS ring (24 KB
// each), counted vmcnt(6) prefetch-1 (R4-verified), bank swizzle kg^((lr>>1)&3) with
// inverse-swizzled global source (R6-verified), XCD-bijective remap (25 consecutive
// blocks share one B panel).  48 KB LDS + ~210 VGPR -> 3 blocks/CU for overlap.
__global__ __launch_bounds__(256, 3) void gemm_kernel(const ushort* __restrict__ A,
                                                      const ushort* __restrict__ B,
                                                      const float* __restrict__ bias,
                                                      ushort* __restrict__ stash, int sstr,
                                                      float* __restrict__ pm,
                                                      float* __restrict__ ps) {
    __shared__ char smem[49152];                 // slot s: A at s*24576, B at s*24576+8192
    const int tid  = threadIdx.x;
    const int w    = tid >> 6;
    const int lane = tid & 63;
    const int wr   = w >> 1, wc = w & 1;
    const int lr   = lane & 15;
    const int kg   = lane >> 4;
    const int kgs  = kg ^ ((lr >> 1) & 3);       // bank-balanced read slot

    // XCD-aware bijective remap: nwg=3125, q=390, r=5
    const int orig = blockIdx.x;
    const int xcd  = orig & 7, seq = orig >> 3;
    const int wgid = (xcd < 5 ? xcd * 391 : 5 * 391 + (xcd - 5) * 390) + seq;
    const int ct   = wgid / NRT;                 // 25 consecutive wgid share one B panel
    const int rt   = wgid - ct * NRT;
    const int brow = rt * 128;
    const int bcol = ct * 256;

    ushort* tileT = (ushort*)smem;
    // staging: A 2 chunks/thread (512), B 4 chunks/thread (1024); inverse-swz source
    const int a0 = tid, a1 = tid + 256;
    const int ar0 = a0 >> 2, as0 = (a0 & 3) ^ ((ar0 >> 1) & 3);
    const int ar1 = a1 >> 2, as1 = (a1 & 3) ^ ((ar1 >> 1) & 3);

    f32x4 acc[4][8];
#pragma unroll
    for (int m = 0; m < 4; ++m)
#pragma unroll
        for (int n = 0; n < 8; ++n)
            acc[m][n] = (f32x4){0.f, 0.f, 0.f, 0.f};

#define STAGE(buf, kt)                                                                      \
    do {                                                                                    \
        char* bA = smem + (buf) * 24576;                                                    \
        char* bB = smem + (buf) * 24576 + 8192;                                             \
        __builtin_amdgcn_global_load_lds(                                                   \
            (const __attribute__((address_space(1))) void*)(A + (size_t)(brow + ar0) * HH + (kt) * 32 + as0 * 8), \
            (__attribute__((address_space(3))) void*)(bA + a0 * 16), 16, 0, 0);             \
        __builtin_amdgcn_global_load_lds(                                                   \
            (const __attribute__((address_space(1))) void*)(A + (size_t)(brow + ar1) * HH + (kt) * 32 + as1 * 8), \
            (__attribute__((address_space(3))) void*)(bA + a1 * 16), 16, 0, 0);             \
        _Pragma("unroll")                                                                   \
        for (int j = 0; j < 4; ++j) {                                                       \
            int c = tid + j * 256;                                                          \
            int row = c >> 2, kcs = (c & 3) ^ ((row >> 1) & 3);                             \
            __builtin_amdgcn_global_load_lds(                                               \
                (const __attribute__((address_space(1))) void*)(B + (size_t)(bcol + row) * HH + (kt) * 32 + kcs * 8), \
                (__attribute__((address_space(3))) void*)(bB + c * 16), 16, 0, 0);          \
        }                                                                                   \
    } while (0)

    STAGE(0, 0);                                 // prologue: tile 0 in flight
    for (int kt = 0; kt < 16; ++kt) {
        const int cur = kt & 1;
        if (kt < 15) {
            STAGE(cur ^ 1, kt + 1);              // next tile's 6 loads fly across barrier
            asm volatile("s_waitcnt vmcnt(6)" ::: "memory");   // cur's 6 retired
        } else {
            asm volatile("s_waitcnt vmcnt(0)" ::: "memory");
        }
        __builtin_amdgcn_sched_barrier(0);
        __builtin_amdgcn_s_barrier();            // all waves: cur tile resident
        __builtin_amdgcn_sched_barrier(0);

        const char* pa = smem + cur * 24576;
        const char* pb = smem + cur * 24576 + 8192;
        bf16x8 af[4], bfr[8];
#pragma unroll
        for (int m = 0; m < 4; ++m)
            af[m] = *(const bf16x8*)(pa + (wr * 64 + m * 16 + lr) * 64 + kgs * 16);
#pragma unroll
        for (int n = 0; n < 8; ++n)
            bfr[n] = *(const bf16x8*)(pb + (wc * 128 + n * 16 + lr) * 64 + kgs * 16);
        __builtin_amdgcn_sched_barrier(0);
        __builtin_amdgcn_s_setprio(1);
#pragma unroll
        for (int m = 0; m < 4; ++m)
#pragma unroll
            for (int n = 0; n < 8; ++n)
                acc[m][n] = __builtin_amdgcn_mfma_f32_16x16x32_bf16(af[m], bfr[n], acc[m][n], 0, 0, 0);
        __builtin_amdgcn_s_setprio(0);
        __builtin_amdgcn_sched_barrier(0);
        __builtin_amdgcn_s_barrier();            // all waves done reading cur
    }
#undef STAGE
    __syncthreads();                             // fence before tileT reuse of smem

    // ---- epilogue: two 128-col half-passes through unioned tileT (128 x 136) ----
    const int prow = tid >> 1, phalf = tid & 1;
    float Mx = -1e30f, Sx = 0.f;
#pragma unroll
    for (int h = 0; h < 2; ++h) {
        if (wc == h) {                           // 2 waves (wr=0,1) own this col-half
#pragma unroll
            for (int n = 0; n < 8; ++n) {
                int col = n * 16 + lr;           // 0..127 within half
                float bv = bias[bcol + h * 128 + col];
#pragma unroll
                for (int m = 0; m < 4; ++m) {
                    int row0 = wr * 64 + m * 16 + kg * 4;
#pragma unroll
                    for (int r = 0; r < 4; ++r)
                        tileT[(row0 + r) * TSTR + col] = f2bf(acc[m][n][r] + bv);
                }
            }
        }
        __syncthreads();

        // coalesced bf16 store of this half (256B runs, 128B-aligned in ws path)
#pragma unroll
        for (int it = 0; it < 8; ++it) {
            int idx = it * 256 + tid;
            int row = idx >> 4, ch = idx & 15;
            uint4 v = *(const uint4*)(&tileT[row * TSTR + ch * 8]);
            *(uint4*)(stash + (size_t)(brow + row) * sstr + bcol + h * 128 + ch * 8) = v;
        }

        // per-row partial (max,sumexp): 2 threads/row, 64 cols each, merged online
        {
            const ushort* trow = &tileT[prow * TSTR + phalf * 64];
            uint4 vv[8];
#pragma unroll
            for (int i = 0; i < 8; ++i) vv[i] = *(const uint4*)(trow + i * 8);
            float mx = -1e30f;
#pragma unroll
            for (int i = 0; i < 8; ++i) {
                mx = fmaxf(mx, fmaxf(fmaxf(bflo(vv[i].x), bfhi(vv[i].x)), fmaxf(bflo(vv[i].y), bfhi(vv[i].y))));
                mx = fmaxf(mx, fmaxf(fmaxf(bflo(vv[i].z), bfhi(vv[i].z)), fmaxf(bflo(vv[i].w), bfhi(vv[i].w))));
            }
            float sx = 0.f;
#pragma unroll
            for (int i = 0; i < 8; ++i) {
                sx += __expf(bflo(vv[i].x) - mx) + __expf(bfhi(vv[i].x) - mx)
                    + __expf(bflo(vv[i].y) - mx) + __expf(bfhi(vv[i].y) - mx)
                    + __expf(bflo(vv[i].z) - mx) + __expf(bfhi(vv[i].z) - mx)
                    + __expf(bflo(vv[i].w) - mx) + __expf(bfhi(vv[i].w) - mx);
            }
            float nm = fmaxf(Mx, mx);
            Sx = Sx * __expf(Mx - nm) + sx * __expf(mx - nm);
            Mx = nm;
        }
        __syncthreads();                         // tileT fully read before next half
    }

    // combine the two 64-col partials (phalf 0/1) and store
    {
        float om = __shfl_xor(Mx, 1), os = __shfl_xor(Sx, 1);
        float M = fmaxf(Mx, om);
        float S = Sx * __expf(Mx - M) + os * __expf(om - M);
        if (phalf == 0) {
            pm[(size_t)ct * MROWS + brow + prow] = M;
            ps[(size_t)ct * MROWS + brow + prow] = S;
        }
    }
}

// ---------------- pass 2 (fused): lse reduce + gate + scatter + normalize ----
__global__ __launch_bounds__(256) void norm_ext_kernel(float* __restrict__ out,
                                                       const ushort* __restrict__ stash,
                                                       int sstr, int inplace,
                                                       const float* __restrict__ pm,
                                                       const float* __restrict__ ps,
                                                       const float* __restrict__ dec,
                                                       const float* __restrict__ wc,
                                                       const float* __restrict__ bcp,
                                                       const float* __restrict__ attn,
                                                       const int* __restrict__ cte) {
    const int r = blockIdx.x;
    const int t = threadIdx.x;
    const int w = t >> 6, lane = t & 63;
    __shared__ float sm[4], ssv[4], red[4];
    __shared__ float lse_sh, csh;
    __shared__ float bins[VE];                   // 20000 B

    // lse partials (125 of them)
    float m = -1e30f, s = 0.f;
    if (t < NTILE) {
        m = pm[(size_t)t * MROWS + r];
        s = ps[(size_t)t * MROWS + r];
    }
    for (int off = 1; off < 64; off <<= 1) {
        float om = __shfl_xor(m, off), os = __shfl_xor(s, off);
        float nm = fmaxf(m, om);
        s = s * __expf(m - nm) + os * __expf(om - nm);
        m = nm;
    }
    if (lane == 0) { sm[w] = m; ssv[w] = s; }

    // gate partial: dot(dec[r], Wc), 2 elems/thread
    {
        float part = dec[(size_t)r * HH + t] * wc[t]
                   + dec[(size_t)r * HH + t + 256] * wc[t + 256];
        for (int off = 1; off < 64; off <<= 1) part += __shfl_xor(part, off);
        if (lane == 0) red[w] = part;
    }
    for (int v = t; v < VE; v += 256) bins[v] = 0.f;
    __syncthreads();

    if (t == 0) {
        float M = sm[0], S = ssv[0];
        for (int i = 1; i < 4; ++i) {
            float nm = fmaxf(M, sm[i]);
            S = S * __expf(M - nm) + ssv[i] * __expf(sm[i] - nm);
            M = nm;
        }
        lse_sh = M + __logf(S);
        float g = red[0] + red[1] + red[2] + red[3] + bcp[0];
        csh = 1.f / (1.f + __expf(-g));
    }
    __syncthreads();
    const float l = lse_sh;
    const float c = csh;

    // ext scatter into LDS bins
    if (t < SS) {
        float aw = attn[(size_t)r * SS + t] * (1.f - c);
        int idx = cte[t * BB + (r & 63)];
        if (idx != 0) atomicAdd(&bins[idx], aw);
    }

    // normalize sweep: bf16 stash -> fp32 log-softmax
    const uint4* gsrc = (const uint4*)(stash + (size_t)r * sstr);
    float4* orow = (float4*)(out + (size_t)r * LDC);
    if (inplace) {
        for (int n = 0; n < 16; ++n) {
            int i = t + 256 * n;
            if (i < VT / 8) {
                uint4 v = gsrc[i];
                float4 a, b;
                a.x = bflo(v.x) - l; a.y = bfhi(v.x) - l;
                a.z = bflo(v.y) - l; a.w = bfhi(v.y) - l;
                b.x = bflo(v.z) - l; b.y = bfhi(v.z) - l;
                b.z = bflo(v.w) - l; b.w = bfhi(v.w) - l;
                orow[2 * i]     = a;
                orow[2 * i + 1] = b;
            }
            if ((n & 1) == 1) __syncthreads();   // bound read/write skew (R4 proof)
        }
    } else {
        for (int i = t; i < VT / 8; i += 256) {
            uint4 v = gsrc[i];
            float4 a, b;
            a.x = bflo(v.x) - l; a.y = bfhi(v.x) - l;
            a.z = bflo(v.y) - l; a.w = bfhi(v.y) - l;
            b.x = bflo(v.z) - l; b.y = bfhi(v.z) - l;
            b.z = bflo(v.w) - l; b.w = bfhi(v.w) - l;
            orow[2 * i]     = a;
            orow[2 * i + 1] = b;
        }
    }
    __syncthreads();

    float4* eo = (float4*)(out + (size_t)r * LDC + VT);
    for (int v = t; v < VE / 4; v += 256) {
        float4 x;
        x.x = __logf(fminf(fmaxf(bins[4 * v + 0], 0.001f), 0.999f));
        x.y = __logf(fminf(fmaxf(bins[4 * v + 1], 0.001f), 0.999f));
        x.z = __logf(fminf(fmaxf(bins[4 * v + 2], 0.001f), 0.999f));
        x.w = __logf(fminf(fmaxf(bins[4 * v + 3], 0.001f), 0.999f));
        eo[v] = x;
    }
}

extern "C" void kernel_launch(void* const* d_in, const int* in_sizes, int n_in,
                              void* d_out, int out_size, void* d_ws, size_t ws_size,
                              hipStream_t stream) {
    const float* hidden = (const float*)d_in[0];
    const float* dec    = (const float*)d_in[1];
    // d_in[2] = concat_c, unused by the reference
    const float* attn   = (const float*)d_in[3];
    const int*   cte    = (const int*)d_in[4];
    const float* W      = (const float*)d_in[5];
    const float* bias   = (const float*)d_in[6];
    const float* Wc     = (const float*)d_in[7];
    const float* bc     = (const float*)d_in[8];
    float* out = (float*)d_out;

    ushort* wsB = (ushort*)d_ws;                       // W bf16  [32000][512]  32.77 MB
    ushort* wsA = wsB + (size_t)VT * HH;               // hidden bf16 [3200][512]
    float*  pm  = (float*)(wsA + (size_t)MROWS * HH);  // partial max [125][3200]
    float*  ps  = pm + (size_t)NTILE * MROWS;          // partial sum [125][3200]

    // bf16 logit stash: ws path if workspace large enough (128B-aligned rows),
    // else fall back to the out-row-tail in-place path.
    const size_t base_off = (size_t)VT * HH * 2 + (size_t)MROWS * HH * 2
                          + 2ull * NTILE * MROWS * 4;
    const size_t base_al  = (base_off + 127) & ~(size_t)127;
    const size_t stash_bytes = (size_t)MROWS * VT * 2;           // 204.8 MB
    ushort* stash;
    int sstr, inplace;
    if (ws_size >= base_al + stash_bytes) {
        stash = (ushort*)((char*)d_ws + base_al);
        sstr = VT;            // 64000 B rows, 128B-aligned
        inplace = 0;
    } else {
        stash = (ushort*)out + 42000;
        sstr = 74000;
        inplace = 1;
    }

    convert_kernel<<<17600, 256, 0, stream>>>(W, hidden, wsB, wsA);
    gemm_kernel<<<NWG, 256, 0, stream>>>(wsA, wsB, bias, stash, sstr, pm, ps);
    norm_ext_kernel<<<MROWS, 256, 0, stream>>>(out, stash, sstr, inplace,
                                               pm, ps, dec, Wc, bc, attn, cte);
}

// Round 10
// 337.889 us; speedup vs baseline: 2.0949x; 2.0949x over previous
//
#include <hip/hip_runtime.h>
#include <hip/hip_bf16.h>

#define TT 50
#define BB 64
#define SS 100
#define HH 512
#define VT 32000
#define VE 5000
#define LDC 37000          // VT + VE
#define MROWS 3200         // T*B
#define NTILE 125          // VT/256 column tiles
#define NRT 25             // M row tiles of 128
#define NWG 3125           // NTILE*NRT
#define TSTR 136           // epilogue LDS tile stride (ushorts, 128+8)

typedef __bf16 bf16x8 __attribute__((ext_vector_type(8)));
typedef float f32x4 __attribute__((ext_vector_type(4)));

__device__ __forceinline__ ushort f2bf(float f) {
    unsigned u = __float_as_uint(f);
    u += 0x7fffu + ((u >> 16) & 1u);   // RNE
    return (ushort)(u >> 16);
}
__device__ __forceinline__ float bflo(unsigned u) { return __uint_as_float(u << 16); }
__device__ __forceinline__ float bfhi(unsigned u) { return __uint_as_float(u & 0xffff0000u); }

// ---------------- pass 0: fp32 -> bf16 conversion of W and hidden ----------------
__global__ void convert_kernel(const float* __restrict__ W, const float* __restrict__ hid,
                               ushort* __restrict__ wsB, ushort* __restrict__ wsA) {
    int g = blockIdx.x * 256 + threadIdx.x;
    const int WG = 4096000;                      // W float4-groups
    float4 v;
    ushort* dst;
    if (g < WG) {
        v = ((const float4*)W)[g];
        dst = wsB + 4 * (size_t)g;
    } else {
        int h = g - WG;
        v = ((const float4*)hid)[h];
        dst = wsA + 4 * (size_t)h;
    }
    ushort4 o;
    o.x = f2bf(v.x); o.y = f2bf(v.y); o.z = f2bf(v.z); o.w = f2bf(v.w);
    *(ushort4*)dst = o;
}

// ---------------- pass 1: bf16 MFMA GEMM, 128x256 block, 4 waves, wave 64x128 --------
// C = A[3200x512]*B^T[32000x512] + bias.  16 K-tiles of BK=32, 2-slot LDS ring (24 KB
// each), counted vmcnt(6) prefetch-1 (R4-verified), bank swizzle kg^((lr>>1)&3) with
// inverse-swizzled global source (R6-verified), XCD-bijective remap.
// __launch_bounds__(256,2): VGPR cap 256 fits the ~210 needed (R9's (256,3) capped at
// 170 and spilled acc to scratch -> 1.1 GB writes, MfmaUtil 8%).  48 KB LDS, 2 blocks/CU.
__global__ __launch_bounds__(256, 2) void gemm_kernel(const ushort* __restrict__ A,
                                                      const ushort* __restrict__ B,
                                                      const float* __restrict__ bias,
                                                      ushort* __restrict__ stash, int sstr,
                                                      float* __restrict__ pm,
                                                      float* __restrict__ ps) {
    __shared__ char smem[49152];                 // slot s: A at s*24576, B at s*24576+8192
    const int tid  = threadIdx.x;
    const int w    = tid >> 6;
    const int lane = tid & 63;
    const int wr   = w >> 1, wc = w & 1;
    const int lr   = lane & 15;
    const int kg   = lane >> 4;
    const int kgs  = kg ^ ((lr >> 1) & 3);       // bank-balanced read slot

    // XCD-aware bijective remap: nwg=3125, q=390, r=5
    const int orig = blockIdx.x;
    const int xcd  = orig & 7, seq = orig >> 3;
    const int wgid = (xcd < 5 ? xcd * 391 : 5 * 391 + (xcd - 5) * 390) + seq;
    const int ct   = wgid / NRT;                 // 25 consecutive wgid share one B panel
    const int rt   = wgid - ct * NRT;
    const int brow = rt * 128;
    const int bcol = ct * 256;

    ushort* tileT = (ushort*)smem;
    // staging: A 2 chunks/thread (512), B 4 chunks/thread (1024); inverse-swz source
    const int a0 = tid, a1 = tid + 256;
    const int ar0 = a0 >> 2, as0 = (a0 & 3) ^ ((ar0 >> 1) & 3);
    const int ar1 = a1 >> 2, as1 = (a1 & 3) ^ ((ar1 >> 1) & 3);

    f32x4 acc[4][8];
#pragma unroll
    for (int m = 0; m < 4; ++m)
#pragma unroll
        for (int n = 0; n < 8; ++n)
            acc[m][n] = (f32x4){0.f, 0.f, 0.f, 0.f};

#define STAGE(buf, kt)                                                                      \
    do {                                                                                    \
        char* bA = smem + (buf) * 24576;                                                    \
        char* bB = smem + (buf) * 24576 + 8192;                                             \
        __builtin_amdgcn_global_load_lds(                                                   \
            (const __attribute__((address_space(1))) void*)(A + (size_t)(brow + ar0) * HH + (kt) * 32 + as0 * 8), \
            (__attribute__((address_space(3))) void*)(bA + a0 * 16), 16, 0, 0);             \
        __builtin_amdgcn_global_load_lds(                                                   \
            (const __attribute__((address_space(1))) void*)(A + (size_t)(brow + ar1) * HH + (kt) * 32 + as1 * 8), \
            (__attribute__((address_space(3))) void*)(bA + a1 * 16), 16, 0, 0);             \
        _Pragma("unroll")                                                                   \
        for (int j = 0; j < 4; ++j) {                                                       \
            int c = tid + j * 256;                                                          \
            int row = c >> 2, kcs = (c & 3) ^ ((row >> 1) & 3);                             \
            __builtin_amdgcn_global_load_lds(                                               \
                (const __attribute__((address_space(1))) void*)(B + (size_t)(bcol + row) * HH + (kt) * 32 + kcs * 8), \
                (__attribute__((address_space(3))) void*)(bB + c * 16), 16, 0, 0);          \
        }                                                                                   \
    } while (0)

    STAGE(0, 0);                                 // prologue: tile 0 in flight
    for (int kt = 0; kt < 16; ++kt) {
        const int cur = kt & 1;
        if (kt < 15) {
            STAGE(cur ^ 1, kt + 1);              // next tile's 6 loads fly across barrier
            asm volatile("s_waitcnt vmcnt(6)" ::: "memory");   // cur's 6 retired
        } else {
            asm volatile("s_waitcnt vmcnt(0)" ::: "memory");
        }
        __builtin_amdgcn_sched_barrier(0);
        __builtin_amdgcn_s_barrier();            // all waves: cur tile resident
        __builtin_amdgcn_sched_barrier(0);

        const char* pa = smem + cur * 24576;
        const char* pb = smem + cur * 24576 + 8192;
        bf16x8 af[4], bfr[8];
#pragma unroll
        for (int m = 0; m < 4; ++m)
            af[m] = *(const bf16x8*)(pa + (wr * 64 + m * 16 + lr) * 64 + kgs * 16);
#pragma unroll
        for (int n = 0; n < 8; ++n)
            bfr[n] = *(const bf16x8*)(pb + (wc * 128 + n * 16 + lr) * 64 + kgs * 16);
        __builtin_amdgcn_sched_barrier(0);
        __builtin_amdgcn_s_setprio(1);
#pragma unroll
        for (int m = 0; m < 4; ++m)
#pragma unroll
            for (int n = 0; n < 8; ++n)
                acc[m][n] = __builtin_amdgcn_mfma_f32_16x16x32_bf16(af[m], bfr[n], acc[m][n], 0, 0, 0);
        __builtin_amdgcn_s_setprio(0);
        __builtin_amdgcn_sched_barrier(0);
        __builtin_amdgcn_s_barrier();            // all waves done reading cur
    }
#undef STAGE
    __syncthreads();                             // fence before tileT reuse of smem

    // ---- epilogue: two 128-col half-passes through unioned tileT (128 x 136) ----
    const int prow = tid >> 1, phalf = tid & 1;
    float Mx = -1e30f, Sx = 0.f;
#pragma unroll
    for (int h = 0; h < 2; ++h) {
        if (wc == h) {                           // 2 waves (wr=0,1) own this col-half
#pragma unroll
            for (int n = 0; n < 8; ++n) {
                int col = n * 16 + lr;           // 0..127 within half
                float bv = bias[bcol + h * 128 + col];
#pragma unroll
                for (int m = 0; m < 4; ++m) {
                    int row0 = wr * 64 + m * 16 + kg * 4;
#pragma unroll
                    for (int r = 0; r < 4; ++r)
                        tileT[(row0 + r) * TSTR + col] = f2bf(acc[m][n][r] + bv);
                }
            }
        }
        __syncthreads();

        // coalesced bf16 store of this half (256B runs, 128B-aligned in ws path)
#pragma unroll
        for (int it = 0; it < 8; ++it) {
            int idx = it * 256 + tid;
            int row = idx >> 4, ch = idx & 15;
            uint4 v = *(const uint4*)(&tileT[row * TSTR + ch * 8]);
            *(uint4*)(stash + (size_t)(brow + row) * sstr + bcol + h * 128 + ch * 8) = v;
        }

        // per-row partial (max,sumexp): 2 threads/row, 64 cols each, merged online
        {
            const ushort* trow = &tileT[prow * TSTR + phalf * 64];
            uint4 vv[8];
#pragma unroll
            for (int i = 0; i < 8; ++i) vv[i] = *(const uint4*)(trow + i * 8);
            float mx = -1e30f;
#pragma unroll
            for (int i = 0; i < 8; ++i) {
                mx = fmaxf(mx, fmaxf(fmaxf(bflo(vv[i].x), bfhi(vv[i].x)), fmaxf(bflo(vv[i].y), bfhi(vv[i].y))));
                mx = fmaxf(mx, fmaxf(fmaxf(bflo(vv[i].z), bfhi(vv[i].z)), fmaxf(bflo(vv[i].w), bfhi(vv[i].w))));
            }
            float sx = 0.f;
#pragma unroll
            for (int i = 0; i < 8; ++i) {
                sx += __expf(bflo(vv[i].x) - mx) + __expf(bfhi(vv[i].x) - mx)
                    + __expf(bflo(vv[i].y) - mx) + __expf(bfhi(vv[i].y) - mx)
                    + __expf(bflo(vv[i].z) - mx) + __expf(bfhi(vv[i].z) - mx)
                    + __expf(bflo(vv[i].w) - mx) + __expf(bfhi(vv[i].w) - mx);
            }
            float nm = fmaxf(Mx, mx);
            Sx = Sx * __expf(Mx - nm) + sx * __expf(mx - nm);
            Mx = nm;
        }
        __syncthreads();                         // tileT fully read before next half
    }

    // combine the two 64-col partials (phalf 0/1) and store
    {
        float om = __shfl_xor(Mx, 1), os = __shfl_xor(Sx, 1);
        float M = fmaxf(Mx, om);
        float S = Sx * __expf(Mx - M) + os * __expf(om - M);
        if (phalf == 0) {
            pm[(size_t)ct * MROWS + brow + prow] = M;
            ps[(size_t)ct * MROWS + brow + prow] = S;
        }
    }
}

// ---------------- pass 2 (fused): lse reduce + gate + scatter + normalize ----
__global__ __launch_bounds__(256) void norm_ext_kernel(float* __restrict__ out,
                                                       const ushort* __restrict__ stash,
                                                       int sstr, int inplace,
                                                       const float* __restrict__ pm,
                                                       const float* __restrict__ ps,
                                                       const float* __restrict__ dec,
                                                       const float* __restrict__ wc,
                                                       const float* __restrict__ bcp,
                                                       const float* __restrict__ attn,
                                                       const int* __restrict__ cte) {
    const int r = blockIdx.x;
    const int t = threadIdx.x;
    const int w = t >> 6, lane = t & 63;
    __shared__ float sm[4], ssv[4], red[4];
    __shared__ float lse_sh, csh;
    __shared__ float bins[VE];                   // 20000 B

    // lse partials (125 of them)
    float m = -1e30f, s = 0.f;
    if (t < NTILE) {
        m = pm[(size_t)t * MROWS + r];
        s = ps[(size_t)t * MROWS + r];
    }
    for (int off = 1; off < 64; off <<= 1) {
        float om = __shfl_xor(m, off), os = __shfl_xor(s, off);
        float nm = fmaxf(m, om);
        s = s * __expf(m - nm) + os * __expf(om - nm);
        m = nm;
    }
    if (lane == 0) { sm[w] = m; ssv[w] = s; }

    // gate partial: dot(dec[r], Wc), 2 elems/thread
    {
        float part = dec[(size_t)r * HH + t] * wc[t]
                   + dec[(size_t)r * HH + t + 256] * wc[t + 256];
        for (int off = 1; off < 64; off <<= 1) part += __shfl_xor(part, off);
        if (lane == 0) red[w] = part;
    }
    for (int v = t; v < VE; v += 256) bins[v] = 0.f;
    __syncthreads();

    if (t == 0) {
        float M = sm[0], S = ssv[0];
        for (int i = 1; i < 4; ++i) {
            float nm = fmaxf(M, sm[i]);
            S = S * __expf(M - nm) + ssv[i] * __expf(sm[i] - nm);
            M = nm;
        }
        lse_sh = M + __logf(S);
        float g = red[0] + red[1] + red[2] + red[3] + bcp[0];
        csh = 1.f / (1.f + __expf(-g));
    }
    __syncthreads();
    const float l = lse_sh;
    const float c = csh;

    // ext scatter into LDS bins
    if (t < SS) {
        float aw = attn[(size_t)r * SS + t] * (1.f - c);
        int idx = cte[t * BB + (r & 63)];
        if (idx != 0) atomicAdd(&bins[idx], aw);
    }

    // normalize sweep: bf16 stash -> fp32 log-softmax
    const uint4* gsrc = (const uint4*)(stash + (size_t)r * sstr);
    float4* orow = (float4*)(out + (size_t)r * LDC);
    if (inplace) {
        for (int n = 0; n < 16; ++n) {
            int i = t + 256 * n;
            if (i < VT / 8) {
                uint4 v = gsrc[i];
                float4 a, b;
                a.x = bflo(v.x) - l; a.y = bfhi(v.x) - l;
                a.z = bflo(v.y) - l; a.w = bfhi(v.y) - l;
                b.x = bflo(v.z) - l; b.y = bfhi(v.z) - l;
                b.z = bflo(v.w) - l; b.w = bfhi(v.w) - l;
                orow[2 * i]     = a;
                orow[2 * i + 1] = b;
            }
            if ((n & 1) == 1) __syncthreads();   // bound read/write skew (R4 proof)
        }
    } else {
        for (int i = t; i < VT / 8; i += 256) {
            uint4 v = gsrc[i];
            float4 a, b;
            a.x = bflo(v.x) - l; a.y = bfhi(v.x) - l;
            a.z = bflo(v.y) - l; a.w = bfhi(v.y) - l;
            b.x = bflo(v.z) - l; b.y = bfhi(v.z) - l;
            b.z = bflo(v.w) - l; b.w = bfhi(v.w) - l;
            orow[2 * i]     = a;
            orow[2 * i + 1] = b;
        }
    }
    __syncthreads();

    float4* eo = (float4*)(out + (size_t)r * LDC + VT);
    for (int v = t; v < VE / 4; v += 256) {
        float4 x;
        x.x = __logf(fminf(fmaxf(bins[4 * v + 0], 0.001f), 0.999f));
        x.y = __logf(fminf(fmaxf(bins[4 * v + 1], 0.001f), 0.999f));
        x.z = __logf(fminf(fmaxf(bins[4 * v + 2], 0.001f), 0.999f));
        x.w = __logf(fminf(fmaxf(bins[4 * v + 3], 0.001f), 0.999f));
        eo[v] = x;
    }
}

extern "C" void kernel_launch(void* const* d_in, const int* in_sizes, int n_in,
                              void* d_out, int out_size, void* d_ws, size_t ws_size,
                              hipStream_t stream) {
    const float* hidden = (const float*)d_in[0];
    const float* dec    = (const float*)d_in[1];
    // d_in[2] = concat_c, unused by the reference
    const float* attn   = (const float*)d_in[3];
    const int*   cte    = (const int*)d_in[4];
    const float* W      = (const float*)d_in[5];
    const float* bias   = (const float*)d_in[6];
    const float* Wc     = (const float*)d_in[7];
    const float* bc     = (const float*)d_in[8];
    float* out = (float*)d_out;

    ushort* wsB = (ushort*)d_ws;                       // W bf16  [32000][512]  32.77 MB
    ushort* wsA = wsB + (size_t)VT * HH;               // hidden bf16 [3200][512]
    float*  pm  = (float*)(wsA + (size_t)MROWS * HH);  // partial max [125][3200]
    float*  ps  = pm + (size_t)NTILE * MROWS;          // partial sum [125][3200]

    // bf16 logit stash: ws path if workspace large enough (128B-aligned rows),
    // else fall back to the out-row-tail in-place path.
    const size_t base_off = (size_t)VT * HH * 2 + (size_t)MROWS * HH * 2
                          + 2ull * NTILE * MROWS * 4;
    const size_t base_al  = (base_off + 127) & ~(size_t)127;
    const size_t stash_bytes = (size_t)MROWS * VT * 2;           // 204.8 MB
    ushort* stash;
    int sstr, inplace;
    if (ws_size >= base_al + stash_bytes) {
        stash = (ushort*)((char*)d_ws + base_al);
        sstr = VT;            // 64000 B rows, 128B-aligned
        inplace = 0;
    } else {
        stash = (ushort*)out + 42000;
        sstr = 74000;
        inplace = 1;
    }

    convert_kernel<<<17600, 256, 0, stream>>>(W, hidden, wsB, wsA);
    gemm_kernel<<<NWG, 256, 0, stream>>>(wsA, wsB, bias, stash, sstr, pm, ps);
    norm_ext_kernel<<<MROWS, 256, 0, stream>>>(out, stash, sstr, inplace,
                                               pm, ps, dec, Wc, bc, attn, cte);
}